// Round 7
// baseline (350.862 us; speedup 1.0000x reference)
//
#include <hip/hip_runtime.h>

// TGNN encoder v8 — v7 (LDS overlay -> 2 blocks/CU) hardened: flat shared buffer
// + aliased pointers instead of a __shared__ union (round-6 bench was an infra
// failure; union was the only unusual construct, so removed for safety).
// B=1024, N=200, DN=DT=128, M=384.
// v6 post-mortem: K-split partial buffers (+22KB LDS -> 61.5KB) dropped residency
// to 1 block/CU (Occupancy 91->44): L2-GEMV phases of one block could no longer
// overlap the other block's HBM main loop. Empirical 2-block boundary: <=48.6KB.
// Overlay: s_oa (16x384 = 24.6KB) dies at the normalize barrier; fc/w1/w2 K-split
// partials (22.5KB) are born after it -> share one region. LDS ~39.3KB.
// Window structure unchanged: main 13 (depth-1 prefetch) + fc 12 + w1 8 + w2 2.
// d_out layout: [ out (1024*128 f32) | attn_w (1024*200 f32) ]

constexpr int B_   = 1024;
constexpr int N_   = 200;
constexpr int DN_  = 128;
constexpr int DT_  = 128;
constexpr int M_   = 384;       // DN + DN + DT
constexpr int BDIM = 1024;      // 16 waves
constexpr int ROWS = 2;         // batch rows per block
constexpr int WPR  = 8;         // waves per row
constexpr int NPW  = N_ / WPR;  // 25 keys per wave
constexpr int ITER = (NPW + 1) / 2;  // 13 pair-iterations (last has a half-1 tail)

__device__ float g_fcT[M_ * M_];                 // [j][i] = fc_w[i][j]
__device__ float g_w1T[(M_ + DN_) * (2 * DN_)];  // [j][i] = w1[i][j], j<512, i<256
__device__ float g_w2T[(2 * DN_) * DN_];         // [j][i] = w2[i][j], j<256, i<128

__device__ __forceinline__ float half_sum(float v) {   // sum+broadcast within each 32-lane half
#pragma unroll
    for (int off = 16; off > 0; off >>= 1) v += __shfl_xor(v, off, 64);
    return v;
}
__device__ __forceinline__ float wave_sum(float v) {   // full 64-lane sum+broadcast
#pragma unroll
    for (int off = 32; off > 0; off >>= 1) v += __shfl_xor(v, off, 64);
    return v;
}

__global__ void transpose_weights(const float* __restrict__ fc_w,
                                  const float* __restrict__ w1,
                                  const float* __restrict__ w2) {
    const int stride = gridDim.x * blockDim.x;
    for (int idx = blockIdx.x * blockDim.x + threadIdx.x; idx < M_ * M_; idx += stride) {
        const int j = idx / M_, i = idx - j * M_;
        g_fcT[idx] = fc_w[i * M_ + j];
    }
    for (int idx = blockIdx.x * blockDim.x + threadIdx.x; idx < (M_ + DN_) * (2 * DN_); idx += stride) {
        const int j = idx >> 8, i = idx & 255;
        g_w1T[idx] = w1[i * (M_ + DN_) + j];
    }
    for (int idx = blockIdx.x * blockDim.x + threadIdx.x; idx < (2 * DN_) * DN_; idx += stride) {
        const int j = idx >> 7, i = idx & 127;
        g_w2T[idx] = w2[i * (2 * DN_) + j];
    }
}

__global__ __launch_bounds__(BDIM)
void tgnn_kernel(
    const float* __restrict__ src,      // (B, DN)
    const float* __restrict__ src_t,    // (B, 1, DT)
    const float* __restrict__ seq,      // (B, N, DN)
    const float* __restrict__ seq_t,    // (B, N, DT)
    const float* __restrict__ seq_e,    // (B, N, DN)
    const int*   __restrict__ mask,     // (B, N) int32 (bool)
    const float* __restrict__ shared_attn, // (2M,)
    const float* __restrict__ ln_g,     // (M,)
    const float* __restrict__ ln_b,     // (M,)
    float* __restrict__ out,            // (B, DN)
    float* __restrict__ attn_out)       // (B, N)
{
    const int blk  = blockIdx.x;
    const int tid  = threadIdx.x;
    const int wave = tid >> 6;       // 0..15
    const int lane = tid & 63;
    const int row  = wave >> 3;      // 0/1: which batch row in this block
    const int wir  = wave & 7;       // wave index within row (0..7)
    const int b    = blk * ROWS + row;
    const int half = lane >> 5;      // 0/1: key within pair
    const int sub  = lane & 31;
    const int c0   = 4 * sub;        // element base within a 128-slice

    __shared__ float s_p[ROWS][N_];          // unnormalized exp(score)        1.6 KB
    __shared__ float s_q[ROWS][M_];          // q = [src, 0, src_t]            3   KB
    __shared__ float s_x[ROWS][M_];          // normalized attn @ k            3   KB
    __shared__ float s_y[ROWS][M_ + DN_];    // LN output ++ src               4   KB
    __shared__ float s_h[ROWS][2 * DN_];     // relu(x @ w1.T)                 2   KB
    __shared__ int   s_mask[ROWS][N_];       //                                1.6 KB
    __shared__ float s_red[ROWS][16];        // Z partials / LN sums           0.13KB
    // Phase-disjoint overlay region (24.6KB):
    //   phase A: oa[16][384]  — per-wave weighted-sum partials (dies at normalize barrier)
    //   phase B: fcp[2][2][384] (3KB) | w1p[4][2][256] (8KB) | w2p[8][2][128] (8KB)
    __shared__ float s_ovl[16 * M_];
    float (*oa)[M_]        = reinterpret_cast<float (*)[M_]>(s_ovl);                 // [16][384]
    float (*fcp)[ROWS][M_] = reinterpret_cast<float (*)[ROWS][M_]>(s_ovl);           // [2][2][384]
    float (*w1p)[ROWS][256] = reinterpret_cast<float (*)[ROWS][256]>(s_ovl + 2 * ROWS * M_);        // [4][2][256]
    float (*w2p)[ROWS][128] = reinterpret_cast<float (*)[ROWS][128]>(s_ovl + 2 * ROWS * M_ + 4 * ROWS * 256); // [8][2][128]

    // ---- stage q and mask for both rows (coalesced) ----
    for (int idx = tid; idx < ROWS * M_; idx += BDIM) {
        const int r = idx / M_, d = idx - r * M_;
        const int bb = blk * ROWS + r;
        float v = (d < DN_) ? src[bb * DN_ + d]
                            : (d < 2 * DN_ ? 0.0f : src_t[bb * DT_ + (d - 2 * DN_)]);
        s_q[r][d] = v;
    }
    for (int idx = tid; idx < ROWS * N_; idx += BDIM) {
        const int r = idx / N_, n = idx - r * N_;
        s_mask[r][n] = mask[(blk * ROWS + r) * N_ + n];
    }

    // ---- per-lane weight fragments (global, L2-hot; same for both halves) ----
    const float* wq = shared_attn;
    const float* wk = shared_attn + M_;
    const float4 wkA = *(const float4*)&wk[c0];
    const float4 wkE = *(const float4*)&wk[DN_ + c0];
    const float4 wkT = *(const float4*)&wk[2 * DN_ + c0];
    const float4 wqA = *(const float4*)&wq[c0];
    const float4 wqT = *(const float4*)&wq[2 * DN_ + c0];

    __syncthreads();

    // ---- q-side score (constant over n) ----
    const float4 qa = *(const float4*)&s_q[row][c0];
    const float4 qt = *(const float4*)&s_q[row][2 * DN_ + c0];
    float qp = qa.x * wqA.x + qa.y * wqA.y + qa.z * wqA.z + qa.w * wqA.w
             + qt.x * wqT.x + qt.y * wqT.y + qt.z * wqT.z + qt.w * wqT.w;
    const float qdot = half_sum(qp);

    // ---- fused score + online weighted-sum, depth-1 prefetch ----
    // Wave handles keys [wir*25, wir*25+25); 13 pair-iters, last has a half-1 tail.
    const int kbase = wir * NPW;
    const float* baseA = seq   + (long)b * (N_ * DN_);
    const float* baseE = seq_e + (long)b * (N_ * DN_);
    const float* baseT = seq_t + (long)b * (N_ * DT_);

    float4 oA = make_float4(0.f, 0.f, 0.f, 0.f);
    float4 oE = oA, oT = oA;
    float lsum = 0.f;

    // preload window 0 (it=0 is always valid for both halves)
    {
        const int off0 = (kbase + half) * DN_ + c0;
        float4 a = *(const float4*)(baseA + off0);
        float4 e = *(const float4*)(baseE + off0);
        float4 t = *(const float4*)(baseT + off0);

        int iters = ITER;
        asm volatile("" : "+s"(iters));           // opaque bound: no unroll
#pragma unroll 1
        for (int it = 0; it < iters; ++it) {
            // current window's key
            const int  ko_c  = 2 * it + half;
            const bool val_c = ko_c < NPW;
            const int  n_c   = kbase + (val_c ? ko_c : NPW - 1);
            // issue next window's loads (clamped at the end)
            const int  itn   = (it + 1 < ITER) ? it + 1 : it;
            const int  ko_n  = 2 * itn + half;
            const int  n_n   = kbase + ((ko_n < NPW) ? ko_n : NPW - 1);
            const int  off_n = n_n * DN_ + c0;
            const float4 an = *(const float4*)(baseA + off_n);
            const float4 en = *(const float4*)(baseE + off_n);
            const float4 tn = *(const float4*)(baseT + off_n);
            // compute with current window while next flies
            float part = a.x * wkA.x + a.y * wkA.y + a.z * wkA.z + a.w * wkA.w
                       + e.x * wkE.x + e.y * wkE.y + e.z * wkE.z + e.w * wkE.w
                       + t.x * wkT.x + t.y * wkT.y + t.z * wkT.z + t.w * wkT.w;
            part = half_sum(part);                // per-half sum, broadcast
            const float p = (val_c && !s_mask[row][n_c]) ? __expf(part + qdot) : 0.0f;
            if (sub == 0 && val_c) s_p[row][n_c] = p;
            lsum += p;                            // uniform across the half
            oA.x += p * a.x; oA.y += p * a.y; oA.z += p * a.z; oA.w += p * a.w;
            oE.x += p * e.x; oE.y += p * e.y; oE.z += p * e.z; oE.w += p * e.w;
            oT.x += p * t.x; oT.y += p * t.y; oT.z += p * t.z; oT.w += p * t.w;
            a = an; e = en; t = tn;
        }
    }

    // ---- combine the two halves of the wave ----
    oA.x += __shfl_xor(oA.x, 32, 64); oA.y += __shfl_xor(oA.y, 32, 64);
    oA.z += __shfl_xor(oA.z, 32, 64); oA.w += __shfl_xor(oA.w, 32, 64);
    oE.x += __shfl_xor(oE.x, 32, 64); oE.y += __shfl_xor(oE.y, 32, 64);
    oE.z += __shfl_xor(oE.z, 32, 64); oE.w += __shfl_xor(oE.w, 32, 64);
    oT.x += __shfl_xor(oT.x, 32, 64); oT.y += __shfl_xor(oT.y, 32, 64);
    oT.z += __shfl_xor(oT.z, 32, 64); oT.w += __shfl_xor(oT.w, 32, 64);
    lsum += __shfl_xor(lsum, 32, 64);
    if (lane == 0) s_red[row][wir] = lsum;
    if (half == 0) {
        *(float4*)&oa[wave][c0]            = oA;
        *(float4*)&oa[wave][DN_ + c0]      = oE;
        *(float4*)&oa[wave][2 * DN_ + c0]  = oT;
    }
    __syncthreads();

    // ---- normalize: attn output vector + attention weights (all threads) ----
    for (int idx = tid; idx < ROWS * M_; idx += BDIM) {
        const int r = idx / M_, d = idx - r * M_;
        const float Z = s_red[r][0] + s_red[r][1] + s_red[r][2] + s_red[r][3]
                      + s_red[r][4] + s_red[r][5] + s_red[r][6] + s_red[r][7];
        const float invZ = 1.0f / Z;
        float acc = 0.f;
#pragma unroll
        for (int w = 0; w < 8; ++w) acc += oa[8 * r + w][d];
        s_x[r][d] = acc * invZ;
    }
    for (int idx = tid; idx < ROWS * N_; idx += BDIM) {
        const int r = idx / N_, nn = idx - r * N_;
        const float Z = s_red[r][0] + s_red[r][1] + s_red[r][2] + s_red[r][3]
                      + s_red[r][4] + s_red[r][5] + s_red[r][6] + s_red[r][7];
        attn_out[(blk * ROWS + r) * N_ + nn] = s_p[r][nn] * (1.0f / Z);
    }
    __syncthreads();   // oa dead from here; fcp/w1p/w2p reuse its storage

    // ---- fc: dual-row, K-split 2-way, unroll 16 -> 12 windows (768 threads) ----
    if (tid < 2 * M_) {
        const int kk = (tid >= M_) ? 1 : 0;
        const int i  = tid - kk * M_;
        const int j0 = kk * (M_ / 2);
        float acc0 = 0.f, acc1 = 0.f;
#pragma unroll 16
        for (int j = j0; j < j0 + M_ / 2; ++j) {
            const float w = g_fcT[j * M_ + i];
            acc0 += s_x[0][j] * w;       // LDS broadcast
            acc1 += s_x[1][j] * w;
        }
        fcp[kk][0][i] = acc0;
        fcp[kk][1][i] = acc1;
    }
    __syncthreads();
    for (int idx = tid; idx < ROWS * M_; idx += BDIM) {
        const int r = idx / M_, i = idx - r * M_;
        s_y[r][i] = fcp[0][r][i] + fcp[1][r][i] + s_q[r][i];
    }
    __syncthreads();

    // ---- layer norm over M (per row: 8 waves) ----
    {
        float ls = 0.f, lq = 0.f;
        for (int j = 64 * wir + lane; j < M_; j += 512) {
            const float v = s_y[row][j];
            ls += v; lq += v * v;
        }
        ls = wave_sum(ls); lq = wave_sum(lq);
        if (lane == 0) { s_red[row][wir] = ls; s_red[row][8 + wir] = lq; }
    }
    __syncthreads();
    for (int idx = tid; idx < ROWS * M_; idx += BDIM) {
        const int r = idx / M_, j = idx - r * M_;
        float sm = 0.f, sq2 = 0.f;
#pragma unroll
        for (int w = 0; w < 8; ++w) { sm += s_red[r][w]; sq2 += s_red[r][8 + w]; }
        const float mean = sm * (1.0f / M_);
        const float msq  = sq2 * (1.0f / M_);
        const float rstd = rsqrtf(msq - mean * mean + 1e-5f);
        s_y[r][j] = (s_y[r][j] - mean) * rstd * ln_g[j] + ln_b[j];
    }
    for (int idx = tid; idx < ROWS * DN_; idx += BDIM) {
        const int r = idx >> 7, d = idx & 127;
        s_y[r][M_ + d] = s_q[r][d];       // concat src
    }
    __syncthreads();

    // ---- agg fc1: dual-row, K-split 4-way, unroll 16 -> 8 windows (1024 threads) ----
    {
        const int kk = tid >> 8, i = tid & 255;
        const int j0 = kk * 128;
        float acc0 = 0.f, acc1 = 0.f;
#pragma unroll 16
        for (int j = j0; j < j0 + 128; ++j) {
            const float w = g_w1T[j * 256 + i];
            acc0 += s_y[0][j] * w;
            acc1 += s_y[1][j] * w;
        }
        w1p[kk][0][i] = acc0;
        w1p[kk][1][i] = acc1;
    }
    __syncthreads();
    if (tid < 512) {
        const int r = tid >> 8, i = tid & 255;
        s_h[r][i] = fmaxf(w1p[0][r][i] + w1p[1][r][i] +
                          w1p[2][r][i] + w1p[3][r][i], 0.0f);
    }
    __syncthreads();

    // ---- agg fc2: dual-row, K-split 8-way, unroll 16 -> 2 windows (1024 threads) ----
    {
        const int kk = tid >> 7, i = tid & 127;
        const int j0 = kk * 32;
        float acc0 = 0.f, acc1 = 0.f;
#pragma unroll 16
        for (int j = j0; j < j0 + 32; ++j) {
            const float w = g_w2T[j * 128 + i];
            acc0 += s_h[0][j] * w;
            acc1 += s_h[1][j] * w;
        }
        w2p[kk][0][i] = acc0;
        w2p[kk][1][i] = acc1;
    }
    __syncthreads();
    if (tid < 256) {
        const int r = tid >> 7, i = tid & 127;
        float v = 0.f;
#pragma unroll
        for (int kk = 0; kk < 8; ++kk) v += w2p[kk][r][i];
        out[(blk * ROWS + r) * DN_ + i] = v;
    }
}

extern "C" void kernel_launch(void* const* d_in, const int* in_sizes, int n_in,
                              void* d_out, int out_size, void* d_ws, size_t ws_size,
                              hipStream_t stream) {
    const float* src         = (const float*)d_in[0];
    const float* src_t       = (const float*)d_in[1];
    const float* seq         = (const float*)d_in[2];
    const float* seq_t       = (const float*)d_in[3];
    const float* seq_e       = (const float*)d_in[4];
    const int*   mask        = (const int*)  d_in[5];
    const float* shared_attn = (const float*)d_in[6];
    const float* fc_w        = (const float*)d_in[7];
    const float* ln_g        = (const float*)d_in[8];
    const float* ln_b        = (const float*)d_in[9];
    const float* w1          = (const float*)d_in[10];
    const float* w2          = (const float*)d_in[11];

    float* outp     = (float*)d_out;             // (B, DN)
    float* attn_out = (float*)d_out + B_ * DN_;  // (B, N)

    transpose_weights<<<256, 256, 0, stream>>>(fc_w, w1, w2);
    tgnn_kernel<<<B_ / ROWS, BDIM, 0, stream>>>(src, src_t, seq, seq_t, seq_e, mask,
                                                shared_attn, ln_g, ln_b, outp, attn_out);
}